// Round 4
// baseline (331.776 us; speedup 1.0000x reference)
//
#include <hip/hip_runtime.h>
#include <hip/hip_bf16.h>
#include <cstddef>

#define B_SZ 2
#define SEQ  2048
#define DM   1024
#define NH   16
#define HD   64
#define LAT  256
#define MTOT (B_SZ*SEQ)   // 4096
#define NQKV 1536
#define QSCALE 0.18033688011112042f  // 0.125 * log2(e)

typedef short bf16x8 __attribute__((ext_vector_type(8)));
typedef float floatx4 __attribute__((ext_vector_type(4)));
typedef float floatx16 __attribute__((ext_vector_type(16)));
typedef unsigned short u16;

#if __has_builtin(__builtin_amdgcn_exp2f)
#define EXP2(x) __builtin_amdgcn_exp2f(x)
#else
#define EXP2(x) exp2f(x)
#endif

__device__ __forceinline__ u16 f2bf(float f) {
  union { float f; unsigned u; } a; a.f = f;
  unsigned r = a.u + 0x7FFFu + ((a.u >> 16) & 1u);  // RNE
  return (u16)(r >> 16);
}

__device__ __forceinline__ floatx4 mfma16(bf16x8 a, bf16x8 b, floatx4 c) {
  return __builtin_amdgcn_mfma_f32_16x16x32_bf16(a, b, c, 0, 0, 0);
}

__device__ __forceinline__ floatx16 mfma32(bf16x8 a, bf16x8 b, floatx16 c) {
  return __builtin_amdgcn_mfma_f32_32x32x16_bf16(a, b, c, 0, 0, 0);
}

// async global->LDS, 16B per lane; lds dest = wave-uniform base + lane*16
__device__ __forceinline__ void load16(const u16* g, u16* l) {
  __builtin_amdgcn_global_load_lds((const __attribute__((address_space(1))) unsigned*)g,
                                   (__attribute__((address_space(3))) unsigned*)l, 16, 0, 0);
}

// ---------------- mega prep: cast x | 6 weight transposes | bias concat ----------------
__device__ void transpose_tile(const float* __restrict__ W, u16* __restrict__ WT,
                               int K, int N, int k0, int n0, u16 (*t)[65]) {
  const int r = threadIdx.x >> 4;          // 0..15
  const int c4 = (threadIdx.x & 15) * 4;   // 0..60
#pragma unroll
  for (int s = 0; s < 4; s++) {
    int row = s * 16 + r;
    float4 v = *(const float4*)&W[(size_t)(k0 + row) * N + n0 + c4];
    t[row][c4 + 0] = f2bf(v.x); t[row][c4 + 1] = f2bf(v.y);
    t[row][c4 + 2] = f2bf(v.z); t[row][c4 + 3] = f2bf(v.w);
  }
  __syncthreads();
  const int r2 = threadIdx.x >> 2;          // 0..63 (out row = n)
  const int c8 = (threadIdx.x & 3) * 16;    // 0,16,32,48 (out col = k)
  __align__(16) u16 tmp[16];
#pragma unroll
  for (int i = 0; i < 16; i++) tmp[i] = t[c8 + i][r2];
  u16* dst = WT + (size_t)(n0 + r2) * K + k0 + c8;
  *(bf16x8*)dst       = *(const bf16x8*)&tmp[0];
  *(bf16x8*)(dst + 8) = *(const bf16x8*)&tmp[8];
}

__global__ __launch_bounds__(256)
void prep_k(const float* __restrict__ x, u16* __restrict__ xb,
            const float* __restrict__ Wq, const float* __restrict__ Wkd,
            const float* __restrict__ Wvd, const float* __restrict__ Wku,
            const float* __restrict__ Wvu, const float* __restrict__ Wo,
            u16* __restrict__ WstkT, u16* __restrict__ WkuT,
            u16* __restrict__ WvuT, u16* __restrict__ WoT,
            const float* __restrict__ bq, const float* __restrict__ bkd,
            const float* __restrict__ bvd, float* __restrict__ bqkv) {
  __shared__ u16 t[64][65];
  const int blk = blockIdx.x;
  if (blk < 4096) {                 // cast x -> bf16, 1 float4/thread
    int i = blk * 256 + threadIdx.x;
    float4 v = ((const float4*)x)[i];
    ushort4 o; o.x = f2bf(v.x); o.y = f2bf(v.y); o.z = f2bf(v.z); o.w = f2bf(v.w);
    ((ushort4*)xb)[i] = o;
  } else if (blk < 4352) {          // Wq^T -> WstkT[0:1024]
    int tt = blk - 4096;
    transpose_tile(Wq, WstkT, DM, DM, (tt >> 4) * 64, (tt & 15) * 64, t);
  } else if (blk < 4416) {          // Wkd^T -> WstkT[1024:1280]
    int tt = blk - 4352;
    transpose_tile(Wkd, WstkT + (size_t)DM * DM, DM, LAT, (tt >> 2) * 64, (tt & 3) * 64, t);
  } else if (blk < 4480) {          // Wvd^T -> WstkT[1280:1536]
    int tt = blk - 4416;
    transpose_tile(Wvd, WstkT + (size_t)1280 * DM, DM, LAT, (tt >> 2) * 64, (tt & 3) * 64, t);
  } else if (blk < 4544) {          // Wku^T
    int tt = blk - 4480;
    transpose_tile(Wku, WkuT, LAT, DM, (tt >> 4) * 64, (tt & 15) * 64, t);
  } else if (blk < 4608) {          // Wvu^T
    int tt = blk - 4544;
    transpose_tile(Wvu, WvuT, LAT, DM, (tt >> 4) * 64, (tt & 15) * 64, t);
  } else if (blk < 4864) {          // Wo^T
    int tt = blk - 4608;
    transpose_tile(Wo, WoT, DM, DM, (tt >> 4) * 64, (tt & 15) * 64, t);
  } else {                          // bias concat (6 blocks)
    int i = (blk - 4864) * 256 + threadIdx.x;
    float v = (i < 1024) ? bq[i] : (i < 1280) ? bkd[i - 1024] : bvd[i - 1280];
    bqkv[i] = v;
  }
}

// ---------------- GEMM: C = A * BT^T + bias ----------------
// TM x 64 block tile (TM=128 or 64) -> 2-4x more blocks/CU than 128x128 so the
// 2-barrier K-loop's vmcnt drain is hidden by co-resident blocks [R5 post-mortem].
// VT1: when blockIdx.z==1, write C in VT[bh][d][s] layout (fused V-transpose).
template<int TM, int OUT_BF16, int VT1>
__global__ __launch_bounds__(256)
void gemm_bt(const u16* __restrict__ A0, const u16* __restrict__ A1,
             const u16* __restrict__ BT0, const u16* __restrict__ BT1,
             const float* __restrict__ bias0, const float* __restrict__ bias1,
             void* __restrict__ C0, void* __restrict__ C1,
             int M, int N, int Kd, int lda, float qscale, int qcols) {
  constexpr int FM = TM / 32;       // frags per wave along M
  __shared__ u16 As[TM * 64];
  __shared__ u16 Bs[64 * 64];
  const u16* A  = blockIdx.z ? A1 : A0;
  const u16* BT = blockIdx.z ? BT1 : BT0;
  const float* bias = blockIdx.z ? bias1 : bias0;
  void* C = blockIdx.z ? C1 : C0;

  const int tid = threadIdx.x;
  const int m0 = blockIdx.y * TM, n0 = blockIdx.x * 64;
  const int wave = tid >> 6, lane = tid & 63;
  const int l15 = lane & 15, quad = lane >> 4;
  const int wm = (wave >> 1) * (TM / 2), wn = (wave & 1) * 32;

  floatx4 acc[FM][2];
#pragma unroll
  for (int i = 0; i < FM; i++)
#pragma unroll
    for (int j = 0; j < 2; j++) acc[i][j] = (floatx4){0.f, 0.f, 0.f, 0.f};

  const int tr = tid >> 3;          // 0..31
  const int tc8 = (tid & 7) * 8;
  const u16* Ag = A  + (size_t)(m0 + tr) * lda + tc8;
  const u16* Bg = BT + (size_t)(n0 + tr) * Kd + tc8;
  u16* AsW = &As[(size_t)tid * 8];
  u16* BsW = &Bs[(size_t)tid * 8];

  for (int k0 = 0; k0 < Kd; k0 += 64) {
    __syncthreads();
#pragma unroll
    for (int s = 0; s < FM; s++)
      load16(Ag + (size_t)(s * 32) * lda + k0, AsW + s * 2048);
#pragma unroll
    for (int s = 0; s < 2; s++)
      load16(Bg + (size_t)(s * 32) * Kd  + k0, BsW + s * 2048);
    __syncthreads();
#pragma unroll
    for (int kk = 0; kk < 2; kk++) {
      bf16x8 af[FM], bfr[2];
#pragma unroll
      for (int i = 0; i < FM; i++)
        af[i]  = *(const bf16x8*)&As[(wm + i * 16 + l15) * 64 + kk * 32 + quad * 8];
#pragma unroll
      for (int j = 0; j < 2; j++)
        bfr[j] = *(const bf16x8*)&Bs[(wn + j * 16 + l15) * 64 + kk * 32 + quad * 8];
#pragma unroll
      for (int i = 0; i < FM; i++)
#pragma unroll
        for (int j = 0; j < 2; j++)
          acc[i][j] = mfma16(af[i], bfr[j], acc[i][j]);
    }
  }

  if (VT1 && blockIdx.z == 1) {
    // write V in transposed per-head layout: VT[(b*16+h)*64+d][s]
#pragma unroll
    for (int i = 0; i < FM; i++) {
      int row = m0 + wm + i * 16 + quad * 4;    // b*2048 + s (s ≡ 0 mod 4)
      int bb = row >> 11, sb = row & 2047;
#pragma unroll
      for (int j = 0; j < 2; j++) {
        int col = n0 + wn + j * 16 + l15;       // h*64 + d
        float bv = bias[col];
        union { u16 u[4]; uint2 w2; } tv;
#pragma unroll
        for (int r = 0; r < 4; r++) tv.u[r] = f2bf(acc[i][j][r] + bv);
        *(uint2*)((u16*)C + ((size_t)(bb * 16 + (col >> 6)) * 64 + (col & 63)) * SEQ + sb) = tv.w2;
      }
    }
  } else {
#pragma unroll
    for (int i = 0; i < FM; i++) {
      int row = m0 + wm + i * 16 + quad * 4;
#pragma unroll
      for (int j = 0; j < 2; j++) {
        int col = n0 + wn + j * 16 + l15;
        float bv = bias[col];
        float sc = (col < qcols) ? qscale : 1.f;
#pragma unroll
        for (int r = 0; r < 4; r++) {
          float v = (acc[i][j][r] + bv) * sc;
          if (OUT_BF16) ((u16*)C)[(size_t)(row + r) * N + col] = f2bf(v);
          else          ((float*)C)[(size_t)(row + r) * N + col] = v;
        }
      }
    }
  }
}

// ---------------- fused attention (LDS-staged K/V, 8 waves, 4/SIMD target) ----------------
// R3 post-mortem: R1 (16x16+LDS-P) and R3 (32x32, zero-LDS) both land at 76us /
// MfmaUtil 17.6% — the shared bound is (i) 2 waves/SIMD occupancy leaving the
// ~1000cy/iter dependency chain exposed, and (ii) scattered per-lane K/V loads
// (each bf16x8 load = 32 cache-line transactions; 8/iter/wave). This version:
//  * block = 128 q-rows, 512 threads: 4 q-waves (32q each, full key range per
//    kw-half) x 2 key-halves -> per-wave state shrinks to o[2] (32 AGPR) +
//    qf 16 + transients; __launch_bounds__(512,4) caps at 128 regs -> 4 waves/SIMD.
//  * K/V tiles (64 keys/iter per kw-half) staged cooperatively into LDS with
//    global_load_lds, coalesced (4 instrs/wave/iter), shared by 4 q-waves ->
//    4x fewer L1 transactions, all linear.
//  * XOR swizzle via PRE-SWIZZLED SOURCE addr + matching swizzled ds_read (rule
//    #21: same involution both sides; chunk' = chunk ^ (row&7)) -> breaks the
//    32-way stride-128B bank conflict.
//  * epilogue: single 2-way combine (kw=1 -> LDS -> kw=0 adds, normalizes).
//  * grid 512 blocks; XCD remap: lin%8 owns 4 bh -> K/V set fits per-XCD L2
//    (kept from R1: FETCH 69.7->12.4MB).
// Spill alarm: WRITE_SIZE >> 8.2MB means the (512,4) cap spilled [R4 lesson].
__global__ __launch_bounds__(512, 4)
void attn_fused(const u16* __restrict__ Q, const u16* __restrict__ K,
                const u16* __restrict__ VT, u16* __restrict__ CTX) {
  // [K/V][kw][buf][row(64)][64 u16 = 128B]  = 64 KiB
  __shared__ __align__(16) u16 KVt[2][2][2][64][64];
  const int lin = blockIdx.y * gridDim.x + blockIdx.x;
  const int idx = lin >> 3;
  const int bh = (lin & 7) * 4 + (idx >> 4);   // XCD (lin%8) owns bh group of 4
  const int q0 = (idx & 15) * 128;
  const int b = bh >> 4, h = bh & 15;
  const int wave = threadIdx.x >> 6, lane = threadIdx.x & 63;
  const int qw = wave & 3;                     // q sub-tile 0..3
  const int kw = wave >> 2;                    // key half 0/1
  const int l31 = lane & 31;
  const int hi = lane >> 5;                    // lane half: 0/1
  const int lr = lane >> 3;                    // staging row-within-8 (0..7)
  const int cx = (lane & 7) ^ lr;              // pre-swizzled source chunk

  // Q as B-operand: qf[dc] elem j = Q[q0+qw*32+l31][h*64 + dc*16 + hi*8 + j]
  bf16x8 qf[4];
  {
    const u16* Qp = Q + (size_t)(b * SEQ + q0 + qw * 32 + l31) * NQKV + h * HD + hi * 8;
#pragma unroll
    for (int dc = 0; dc < 4; dc++)
      qf[dc] = *(const bf16x8*)(Qp + dc * 16);
  }

  // staging source pointers (pre-swizzled): wave stages tile rows [qw*16, qw*16+16)
  const u16* Ksrc[2];
  const u16* Vsrc[2];
#pragma unroll
  for (int s = 0; s < 2; s++) {
    int r = qw * 16 + s * 8 + lr;              // tile row (key for K, d for V)
    Ksrc[s] = K + (size_t)(b * SEQ + r) * DM + h * HD + cx * 8;
    Vsrc[s] = VT + ((size_t)bh * HD + r) * SEQ + cx * 8;
  }

  floatx16 o[2];   // [dh]: ctx^T 32x32 tiles (d = dh*32+..., q = l31)
  const floatx16 zf16 = {0.f,0.f,0.f,0.f,0.f,0.f,0.f,0.f,0.f,0.f,0.f,0.f,0.f,0.f,0.f,0.f};
  o[0] = zf16; o[1] = zf16;
  float ls = 0.f;

  // prologue: stage tile 0 of this kw-half
  {
    const int ktb = kw * 1024;
#pragma unroll
    for (int s = 0; s < 2; s++) {
      load16(Ksrc[s] + (size_t)ktb * DM, &KVt[0][kw][0][qw * 16 + s * 8][0]);
      load16(Vsrc[s] + ktb,              &KVt[1][kw][0][qw * 16 + s * 8][0]);
    }
  }
  __syncthreads();

#pragma unroll 2
  for (int t = 0; t < 16; ++t) {
    const int cur = t & 1, nxt = cur ^ 1;
    // stage next 64-key tile (lands during this iter's compute; barrier-drained)
    if (t < 15) {
      const int ktb = kw * 1024 + (t + 1) * 64;
#pragma unroll
      for (int s = 0; s < 2; s++) {
        load16(Ksrc[s] + (size_t)ktb * DM, &KVt[0][kw][nxt][qw * 16 + s * 8][0]);
        load16(Vsrc[s] + ktb,              &KVt[1][kw][nxt][qw * 16 + s * 8][0]);
      }
    }
    // compute on current tile: 64 keys = 2 x 32-key kh phases
#pragma unroll
    for (int kh = 0; kh < 2; kh++) {
      const int rk = kh * 32 + l31;
      bf16x8 kf[4];
#pragma unroll
      for (int dc = 0; dc < 4; dc++)
        kf[dc] = *(const bf16x8*)&KVt[0][kw][cur][rk][((dc * 2 + hi) ^ (l31 & 7)) * 8];
      // ---- QK^T: S^T[32k][32q] ----
      floatx16 z = zf16;
      __builtin_amdgcn_s_setprio(1);
#pragma unroll
      for (int dc = 0; dc < 4; dc++) z = mfma32(kf[dc], qf[dc], z);
      __builtin_amdgcn_s_setprio(0);
      // ---- exp2 + row-sum ----
      float p[16];
#pragma unroll
      for (int r = 0; r < 16; r++) p[r] = EXP2(z[r]);
      ls += (((p[0] + p[1]) + (p[2] + p[3])) + ((p[4] + p[5]) + (p[6] + p[7])))
          + (((p[8] + p[9]) + (p[10] + p[11])) + ((p[12] + p[13]) + (p[14] + p[15])));
      // ---- pack pairs to bf16 words ----
      unsigned wt[8];
#pragma unroll
      for (int i = 0; i < 8; i++) {
        unsigned ua = __float_as_uint(p[2 * i]) + 0x8000u;
        unsigned ub = __float_as_uint(p[2 * i + 1]) + 0x8000u;
        wt[i] = __builtin_amdgcn_perm(ub, ua, 0x07060302u);
      }
      // ---- half-exchange: PV B-operands in registers (m74/m101-verified map) ----
      unsigned sx[8];
#pragma unroll
      for (int i = 0; i < 8; i++) sx[i] = (unsigned)__shfl_xor((int)wt[i], 32);
      union { unsigned u[4]; bf16x8 v; } b0, b1;
      b0.u[0] = hi ? sx[2] : wt[0];
      b0.u[1] = hi ? sx[3] : wt[1];
      b0.u[2] = hi ? wt[2] : sx[0];
      b0.u[3] = hi ? wt[3] : sx[1];
      b1.u[0] = hi ? sx[6] : wt[4];
      b1.u[1] = hi ? sx[7] : wt[5];
      b1.u[2] = hi ? wt[6] : sx[4];
      b1.u[3] = hi ? wt[7] : sx[5];
      // ---- V frags + PV ----
      bf16x8 vf[4];   // [dh*2 + kslot]
#pragma unroll
      for (int j = 0; j < 4; j++) {
        const int dh = j >> 1, ksl = j & 1;
        const int rv = dh * 32 + l31;
        vf[j] = *(const bf16x8*)&KVt[1][kw][cur][rv][((kh * 4 + ksl * 2 + hi) ^ (l31 & 7)) * 8];
      }
      __builtin_amdgcn_s_setprio(1);
#pragma unroll
      for (int dh = 0; dh < 2; dh++) {
        o[dh] = mfma32(vf[dh * 2 + 0], b0.v, o[dh]);
        o[dh] = mfma32(vf[dh * 2 + 1], b1.v, o[dh]);
      }
      __builtin_amdgcn_s_setprio(0);
    }
    __syncthreads();   // next tile landed (vmcnt drain) + cur free for overwrite
  }

  // ---- 2-way key-half combine through LDS (reuse KVt) ----
  float* Osh = (float*)&KVt[0][0][0][0][0];   // [128 q][68 d-padded]
  float* Lsh = Osh + 128 * 68;
  const float lsum = ls + __shfl_xor(ls, 32);
  const int q = qw * 32 + l31;
  if (kw == 1) {
#pragma unroll
    for (int dh = 0; dh < 2; dh++)
#pragma unroll
      for (int g = 0; g < 4; g++) {
        floatx4 tv = {o[dh][4 * g], o[dh][4 * g + 1], o[dh][4 * g + 2], o[dh][4 * g + 3]};
        *(floatx4*)&Osh[q * 68 + dh * 32 + g * 8 + hi * 4] = tv;
      }
    if (hi == 0) Lsh[q] = lsum;
  }
  __syncthreads();
  if (kw == 0) {
    float inv = 1.f / (lsum + Lsh[q]);
    u16* Crow = CTX + (size_t)(b * SEQ + q0 + q) * DM + h * HD + hi * 4;
#pragma unroll
    for (int dh = 0; dh < 2; dh++)
#pragma unroll
      for (int g = 0; g < 4; g++) {
        const float* oc = &Osh[q * 68 + dh * 32 + g * 8 + hi * 4];
        union { u16 u[4]; uint2 w2; } tv;
#pragma unroll
        for (int r = 0; r < 4; r++)
          tv.u[r] = f2bf((o[dh][4 * g + r] + oc[r]) * inv);
        *(uint2*)(Crow + dh * 32 + g * 8) = tv.w2;
      }
  }
}

// ---------------- launch ----------------
extern "C" void kernel_launch(void* const* d_in, const int* in_sizes, int n_in,
                              void* d_out, int out_size, void* d_ws, size_t ws_size,
                              hipStream_t stream) {
  const float* x   = (const float*)d_in[0];
  const float* Wq  = (const float*)d_in[1];
  const float* bq  = (const float*)d_in[2];
  const float* Wkd = (const float*)d_in[3];
  const float* bkd = (const float*)d_in[4];
  const float* Wvd = (const float*)d_in[5];
  const float* bvd = (const float*)d_in[6];
  const float* Wku = (const float*)d_in[7];
  const float* bku = (const float*)d_in[8];
  const float* Wvu = (const float*)d_in[9];
  const float* bvu = (const float*)d_in[10];
  const float* Wo  = (const float*)d_in[11];
  const float* bo  = (const float*)d_in[12];
  float* out = (float*)d_out;

  float* bqkv = (float*)d_ws;
  u16* p = (u16*)((char*)d_ws + 1536 * sizeof(float));
  u16* xb    = p; p += (size_t)MTOT * DM;
  u16* WstkT = p; p += (size_t)NQKV * DM;           // WqT | WkdT | WvdT
  u16* WkuT  = p; p += (size_t)DM * LAT;
  u16* WvuT  = p; p += (size_t)DM * LAT;
  u16* WoT   = p; p += (size_t)DM * DM;
  u16* QKVb  = p; p += (size_t)MTOT * NQKV;         // Q(pre-scaled) | KL | VL
  u16* Kb    = p; p += (size_t)MTOT * DM;
  u16* VTb   = p; p += (size_t)MTOT * DM;
  u16* CXb   = p; p += (size_t)MTOT * DM;

  prep_k<<<4870, 256, 0, stream>>>(x, xb, Wq, Wkd, Wvd, Wku, Wvu, Wo,
                                   WstkT, WkuT, WvuT, WoT, bq, bkd, bvd, bqkv);

  // QKV projection: 24x32 = 768 blocks (3/CU)
  gemm_bt<128, 1, 0><<<dim3(NQKV / 64, MTOT / 128, 1), 256, 0, stream>>>(
      xb, xb, WstkT, WstkT, bqkv, bqkv, QKVb, QKVb, MTOT, NQKV, DM, DM, QSCALE, DM);
  // K-up (row layout) + V-up (transposed layout): 16x32x2 = 1024 blocks (4/CU)
  gemm_bt<128, 1, 1><<<dim3(DM / 64, MTOT / 128, 2), 256, 0, stream>>>(
      QKVb + 1024, QKVb + 1280, WkuT, WvuT, bku, bvu, Kb, VTb, MTOT, DM, LAT, NQKV, 1.f, 0);

  // 512 blocks x 512 threads: 16 q-blocks x 32 bh, XCD-remapped inside
  attn_fused<<<dim3(SEQ / 128, B_SZ * NH), 512, 0, stream>>>(QKVb, Kb, VTb, CXb);

  // output projection: 16x64 = 1024 blocks (4/CU)
  gemm_bt<64, 0, 0><<<dim3(DM / 64, MTOT / 64, 1), 256, 0, stream>>>(
      CXb, CXb, WoT, WoT, bo, bo, out, out, MTOT, DM, DM, DM, 1.f, 0);
}

// Round 5
// 205.513 us; speedup vs baseline: 1.6144x; 1.6144x over previous
//
#include <hip/hip_runtime.h>
#include <hip/hip_bf16.h>
#include <cstddef>

#define B_SZ 2
#define SEQ  2048
#define DM   1024
#define NH   16
#define HD   64
#define LAT  256
#define MTOT (B_SZ*SEQ)   // 4096
#define NQKV 1536
#define QSCALE 0.18033688011112042f  // 0.125 * log2(e)

typedef short bf16x8 __attribute__((ext_vector_type(8)));
typedef float floatx4 __attribute__((ext_vector_type(4)));
typedef float floatx16 __attribute__((ext_vector_type(16)));
typedef unsigned short u16;

#if __has_builtin(__builtin_amdgcn_exp2f)
#define EXP2(x) __builtin_amdgcn_exp2f(x)
#else
#define EXP2(x) exp2f(x)
#endif

__device__ __forceinline__ u16 f2bf(float f) {
  union { float f; unsigned u; } a; a.f = f;
  unsigned r = a.u + 0x7FFFu + ((a.u >> 16) & 1u);  // RNE
  return (u16)(r >> 16);
}

__device__ __forceinline__ floatx4 mfma16(bf16x8 a, bf16x8 b, floatx4 c) {
  return __builtin_amdgcn_mfma_f32_16x16x32_bf16(a, b, c, 0, 0, 0);
}

__device__ __forceinline__ floatx16 mfma32(bf16x8 a, bf16x8 b, floatx16 c) {
  return __builtin_amdgcn_mfma_f32_32x32x16_bf16(a, b, c, 0, 0, 0);
}

// async global->LDS, 16B per lane; lds dest = wave-uniform base + lane*16
__device__ __forceinline__ void load16(const u16* g, u16* l) {
  __builtin_amdgcn_global_load_lds((const __attribute__((address_space(1))) unsigned*)g,
                                   (__attribute__((address_space(3))) unsigned*)l, 16, 0, 0);
}

// ---------------- mega prep: cast x | 6 weight transposes | bias concat ----------------
__device__ void transpose_tile(const float* __restrict__ W, u16* __restrict__ WT,
                               int K, int N, int k0, int n0, u16 (*t)[65]) {
  const int r = threadIdx.x >> 4;          // 0..15
  const int c4 = (threadIdx.x & 15) * 4;   // 0..60
#pragma unroll
  for (int s = 0; s < 4; s++) {
    int row = s * 16 + r;
    float4 v = *(const float4*)&W[(size_t)(k0 + row) * N + n0 + c4];
    t[row][c4 + 0] = f2bf(v.x); t[row][c4 + 1] = f2bf(v.y);
    t[row][c4 + 2] = f2bf(v.z); t[row][c4 + 3] = f2bf(v.w);
  }
  __syncthreads();
  const int r2 = threadIdx.x >> 2;          // 0..63 (out row = n)
  const int c8 = (threadIdx.x & 3) * 16;    // 0,16,32,48 (out col = k)
  __align__(16) u16 tmp[16];
#pragma unroll
  for (int i = 0; i < 16; i++) tmp[i] = t[c8 + i][r2];
  u16* dst = WT + (size_t)(n0 + r2) * K + k0 + c8;
  *(bf16x8*)dst       = *(const bf16x8*)&tmp[0];
  *(bf16x8*)(dst + 8) = *(const bf16x8*)&tmp[8];
}

__global__ __launch_bounds__(256)
void prep_k(const float* __restrict__ x, u16* __restrict__ xb,
            const float* __restrict__ Wq, const float* __restrict__ Wkd,
            const float* __restrict__ Wvd, const float* __restrict__ Wku,
            const float* __restrict__ Wvu, const float* __restrict__ Wo,
            u16* __restrict__ WstkT, u16* __restrict__ WkuT,
            u16* __restrict__ WvuT, u16* __restrict__ WoT,
            const float* __restrict__ bq, const float* __restrict__ bkd,
            const float* __restrict__ bvd, float* __restrict__ bqkv) {
  __shared__ u16 t[64][65];
  const int blk = blockIdx.x;
  if (blk < 4096) {                 // cast x -> bf16, 1 float4/thread
    int i = blk * 256 + threadIdx.x;
    float4 v = ((const float4*)x)[i];
    ushort4 o; o.x = f2bf(v.x); o.y = f2bf(v.y); o.z = f2bf(v.z); o.w = f2bf(v.w);
    ((ushort4*)xb)[i] = o;
  } else if (blk < 4352) {          // Wq^T -> WstkT[0:1024]
    int tt = blk - 4096;
    transpose_tile(Wq, WstkT, DM, DM, (tt >> 4) * 64, (tt & 15) * 64, t);
  } else if (blk < 4416) {          // Wkd^T -> WstkT[1024:1280]
    int tt = blk - 4352;
    transpose_tile(Wkd, WstkT + (size_t)DM * DM, DM, LAT, (tt >> 2) * 64, (tt & 3) * 64, t);
  } else if (blk < 4480) {          // Wvd^T -> WstkT[1280:1536]
    int tt = blk - 4416;
    transpose_tile(Wvd, WstkT + (size_t)1280 * DM, DM, LAT, (tt >> 2) * 64, (tt & 3) * 64, t);
  } else if (blk < 4544) {          // Wku^T
    int tt = blk - 4480;
    transpose_tile(Wku, WkuT, LAT, DM, (tt >> 4) * 64, (tt & 15) * 64, t);
  } else if (blk < 4608) {          // Wvu^T
    int tt = blk - 4544;
    transpose_tile(Wvu, WvuT, LAT, DM, (tt >> 4) * 64, (tt & 15) * 64, t);
  } else if (blk < 4864) {          // Wo^T
    int tt = blk - 4608;
    transpose_tile(Wo, WoT, DM, DM, (tt >> 4) * 64, (tt & 15) * 64, t);
  } else {                          // bias concat (6 blocks)
    int i = (blk - 4864) * 256 + threadIdx.x;
    float v = (i < 1024) ? bq[i] : (i < 1280) ? bkd[i - 1024] : bvd[i - 1280];
    bqkv[i] = v;
  }
}

// ---------------- GEMM: C = A * BT^T + bias ----------------
template<int TM, int OUT_BF16, int VT1>
__global__ __launch_bounds__(256)
void gemm_bt(const u16* __restrict__ A0, const u16* __restrict__ A1,
             const u16* __restrict__ BT0, const u16* __restrict__ BT1,
             const float* __restrict__ bias0, const float* __restrict__ bias1,
             void* __restrict__ C0, void* __restrict__ C1,
             int M, int N, int Kd, int lda, float qscale, int qcols) {
  constexpr int FM = TM / 32;       // frags per wave along M
  __shared__ u16 As[TM * 64];
  __shared__ u16 Bs[64 * 64];
  const u16* A  = blockIdx.z ? A1 : A0;
  const u16* BT = blockIdx.z ? BT1 : BT0;
  const float* bias = blockIdx.z ? bias1 : bias0;
  void* C = blockIdx.z ? C1 : C0;

  const int tid = threadIdx.x;
  const int m0 = blockIdx.y * TM, n0 = blockIdx.x * 64;
  const int wave = tid >> 6, lane = tid & 63;
  const int l15 = lane & 15, quad = lane >> 4;
  const int wm = (wave >> 1) * (TM / 2), wn = (wave & 1) * 32;

  floatx4 acc[FM][2];
#pragma unroll
  for (int i = 0; i < FM; i++)
#pragma unroll
    for (int j = 0; j < 2; j++) acc[i][j] = (floatx4){0.f, 0.f, 0.f, 0.f};

  const int tr = tid >> 3;          // 0..31
  const int tc8 = (tid & 7) * 8;
  const u16* Ag = A  + (size_t)(m0 + tr) * lda + tc8;
  const u16* Bg = BT + (size_t)(n0 + tr) * Kd + tc8;
  u16* AsW = &As[(size_t)tid * 8];
  u16* BsW = &Bs[(size_t)tid * 8];

  for (int k0 = 0; k0 < Kd; k0 += 64) {
    __syncthreads();
#pragma unroll
    for (int s = 0; s < FM; s++)
      load16(Ag + (size_t)(s * 32) * lda + k0, AsW + s * 2048);
#pragma unroll
    for (int s = 0; s < 2; s++)
      load16(Bg + (size_t)(s * 32) * Kd  + k0, BsW + s * 2048);
    __syncthreads();
#pragma unroll
    for (int kk = 0; kk < 2; kk++) {
      bf16x8 af[FM], bfr[2];
#pragma unroll
      for (int i = 0; i < FM; i++)
        af[i]  = *(const bf16x8*)&As[(wm + i * 16 + l15) * 64 + kk * 32 + quad * 8];
#pragma unroll
      for (int j = 0; j < 2; j++)
        bfr[j] = *(const bf16x8*)&Bs[(wn + j * 16 + l15) * 64 + kk * 32 + quad * 8];
#pragma unroll
      for (int i = 0; i < FM; i++)
#pragma unroll
        for (int j = 0; j < 2; j++)
          acc[i][j] = mfma16(af[i], bfr[j], acc[i][j]);
    }
  }

  if (VT1 && blockIdx.z == 1) {
    // write V in transposed per-head layout: VT[(b*16+h)*64+d][s]
#pragma unroll
    for (int i = 0; i < FM; i++) {
      int row = m0 + wm + i * 16 + quad * 4;    // b*2048 + s (s ≡ 0 mod 4)
      int bb = row >> 11, sb = row & 2047;
#pragma unroll
      for (int j = 0; j < 2; j++) {
        int col = n0 + wn + j * 16 + l15;       // h*64 + d
        float bv = bias[col];
        union { u16 u[4]; uint2 w2; } tv;
#pragma unroll
        for (int r = 0; r < 4; r++) tv.u[r] = f2bf(acc[i][j][r] + bv);
        *(uint2*)((u16*)C + ((size_t)(bb * 16 + (col >> 6)) * 64 + (col & 63)) * SEQ + sb) = tv.w2;
      }
    }
  } else {
#pragma unroll
    for (int i = 0; i < FM; i++) {
      int row = m0 + wm + i * 16 + quad * 4;
#pragma unroll
      for (int j = 0; j < 2; j++) {
        int col = n0 + wn + j * 16 + l15;
        float bv = bias[col];
        float sc = (col < qcols) ? qscale : 1.f;
#pragma unroll
        for (int r = 0; r < 4; r++) {
          float v = (acc[i][j][r] + bv) * sc;
          if (OUT_BF16) ((u16*)C)[(size_t)(row + r) * N + col] = f2bf(v);
          else          ((float*)C)[(size_t)(row + r) * N + col] = v;
        }
      }
    }
  }
}

// ---------------- fused attention (coalesced LDS staging, lean registers) ----------------
// R3 plateau diagnosis: per-lane scattered K/V bf16x8 loads = 32 L1 transactions
// per instruction -> TA-bound at ~2850cy/iter (R1 and R3 identical dur despite
// different compute structures). R4 fixed the transactions but (512,4) forced a
// 64-VGPR split of the unified file -> 600MB spill. This version keeps the
// coalesced staging and earns the register budget instead of forcing it:
//  * 256-thread blocks, 4 waves; wave w owns q-rows [q0+w*32, +32) and the FULL
//    2048-key range -> no key-split combine; o = 2 x floatx16 (32 AGPR) only.
//  * K/V 64-key tiles double-buffered in LDS (32 KiB), staged by global_load_lds:
//    4 instr/thread/iter, each wave-instr = 1KB contiguous -> ~8x fewer memory
//    transactions than per-lane loads. Tiles shared by all 4 waves.
//  * XOR swizzle, involution both sides (rule #21): source chunk cx=(l&7)^(l>>3)
//    so LDS[r][c]=G[r][c^(r&7)]; reads use chunk^(row&7). Breaks the 32-way
//    stride-128B conflict (residual 4-way: 1.58x on LDS pipe only, m136).
//  * softmax in two 8-elem halves (exp->pack->shfl->PV per half) to halve
//    transient register pressure.
//  * __launch_bounds__(256,3): cap ~170 regs (est. need ~130 incl AGPR) -> no
//    spill; 3 waves/SIMD, 3 blocks/CU; co-resident blocks hide barrier drains.
//  * grid 512 blocks; XCD remap lin%8 -> 4-bh group per XCD (K/V fits L2).
// Spill alarm: WRITE_SIZE >> 8.2MB means the cap spilled [R4 lesson].
__global__ __launch_bounds__(256, 3)
void attn_fused(const u16* __restrict__ Q, const u16* __restrict__ K,
                const u16* __restrict__ VT, u16* __restrict__ CTX) {
  __shared__ __align__(16) u16 KVt[2][2][64][64];   // [buf][K/V][row][64 u16] = 32 KiB
  const int lin = blockIdx.y * gridDim.x + blockIdx.x;
  const int idx = lin >> 3;
  const int bh = (lin & 7) * 4 + (idx >> 4);   // XCD (lin%8) owns bh group of 4
  const int q0 = (idx & 15) * 128;
  const int b = bh >> 4, h = bh & 15;
  const int wave = threadIdx.x >> 6, lane = threadIdx.x & 63;
  const int l31 = lane & 31;
  const int hi = lane >> 5;                    // lane half: 0/1
  const int lr = lane >> 3;                    // staging row-within-8 (0..7)
  const int cx = (lane & 7) ^ lr;              // pre-swizzled source chunk

  // Q as B-operand: qf[dc] elem j = Q[q0+wave*32+l31][h*64 + dc*16 + hi*8 + j]
  bf16x8 qf[4];
  {
    const u16* Qp = Q + (size_t)(b * SEQ + q0 + wave * 32 + l31) * NQKV + h * HD + hi * 8;
#pragma unroll
    for (int dc = 0; dc < 4; dc++)
      qf[dc] = *(const bf16x8*)(Qp + dc * 16);
  }

  // staging sources (pre-swizzled): wave w stages tile rows w*8+s*32 .. +8
  const u16* Ks[2];
  const u16* Vs[2];
#pragma unroll
  for (int s = 0; s < 2; s++) {
    int r = wave * 8 + s * 32 + lr;            // tile row (key for K, d for V)
    Ks[s] = K + (size_t)(b * SEQ + r) * DM + h * HD + cx * 8;
    Vs[s] = VT + ((size_t)bh * HD + r) * SEQ + cx * 8;
  }

  floatx16 o[2];   // [dh]: ctx^T 32x32 tiles (row d, col q=l31)
  const floatx16 zf16 = {0.f,0.f,0.f,0.f,0.f,0.f,0.f,0.f,0.f,0.f,0.f,0.f,0.f,0.f,0.f,0.f};
  o[0] = zf16; o[1] = zf16;
  float ls = 0.f;

  // prologue: stage tile 0 into buf 0
#pragma unroll
  for (int s = 0; s < 2; s++) {
    load16(Ks[s], &KVt[0][0][wave * 8 + s * 32][0]);
    load16(Vs[s], &KVt[0][1][wave * 8 + s * 32][0]);
  }
  __syncthreads();

#pragma unroll 2
  for (int t = 0; t < 32; ++t) {
    const int cur = t & 1, nxt = cur ^ 1;
    // stage next 64-key tile (lands during this iter's compute; barrier drains)
    if (t < 31) {
      const int kt = (t + 1) * 64;
#pragma unroll
      for (int s = 0; s < 2; s++) {
        load16(Ks[s] + (size_t)kt * DM, &KVt[nxt][0][wave * 8 + s * 32][0]);
        load16(Vs[s] + kt,              &KVt[nxt][1][wave * 8 + s * 32][0]);
      }
    }
    // compute on current tile: 64 keys = 2 x 32-key kh phases
#pragma unroll
    for (int kh = 0; kh < 2; kh++) {
      const int rk = kh * 32 + l31;
      bf16x8 kf[4];
#pragma unroll
      for (int dc = 0; dc < 4; dc++)
        kf[dc] = *(const bf16x8*)&KVt[cur][0][rk][((dc * 2 + hi) ^ (rk & 7)) * 8];
      // ---- QK^T: S^T[32k][32q] ----
      floatx16 z = zf16;
      __builtin_amdgcn_s_setprio(1);
#pragma unroll
      for (int dc = 0; dc < 4; dc++) z = mfma32(kf[dc], qf[dc], z);
      __builtin_amdgcn_s_setprio(0);
      // ---- half A: regs 0..7 -> keys 0..15 of this kh ----
      {
        float p0 = EXP2(z[0]), p1 = EXP2(z[1]), p2 = EXP2(z[2]), p3 = EXP2(z[3]);
        float p4 = EXP2(z[4]), p5 = EXP2(z[5]), p6 = EXP2(z[6]), p7 = EXP2(z[7]);
        ls += ((p0 + p1) + (p2 + p3)) + ((p4 + p5) + (p6 + p7));
        unsigned w0 = __builtin_amdgcn_perm(__float_as_uint(p1) + 0x8000u,
                                            __float_as_uint(p0) + 0x8000u, 0x07060302u);
        unsigned w1 = __builtin_amdgcn_perm(__float_as_uint(p3) + 0x8000u,
                                            __float_as_uint(p2) + 0x8000u, 0x07060302u);
        unsigned w2 = __builtin_amdgcn_perm(__float_as_uint(p5) + 0x8000u,
                                            __float_as_uint(p4) + 0x8000u, 0x07060302u);
        unsigned w3 = __builtin_amdgcn_perm(__float_as_uint(p7) + 0x8000u,
                                            __float_as_uint(p6) + 0x8000u, 0x07060302u);
        unsigned s0 = (unsigned)__shfl_xor((int)w0, 32);
        unsigned s1 = (unsigned)__shfl_xor((int)w1, 32);
        unsigned s2 = (unsigned)__shfl_xor((int)w2, 32);
        unsigned s3 = (unsigned)__shfl_xor((int)w3, 32);
        union { unsigned u[4]; bf16x8 v; } b0;
        b0.u[0] = hi ? s2 : w0;
        b0.u[1] = hi ? s3 : w1;
        b0.u[2] = hi ? w2 : s0;
        b0.u[3] = hi ? w3 : s1;
        bf16x8 vf0 = *(const bf16x8*)&KVt[cur][1][l31     ][((kh * 4 + hi) ^ (l31 & 7)) * 8];
        bf16x8 vf1 = *(const bf16x8*)&KVt[cur][1][32 + l31][((kh * 4 + hi) ^ (l31 & 7)) * 8];
        __builtin_amdgcn_s_setprio(1);
        o[0] = mfma32(vf0, b0.v, o[0]);
        o[1] = mfma32(vf1, b0.v, o[1]);
        __builtin_amdgcn_s_setprio(0);
      }
      // ---- half B: regs 8..15 -> keys 16..31 of this kh ----
      {
        float p0 = EXP2(z[8]),  p1 = EXP2(z[9]),  p2 = EXP2(z[10]), p3 = EXP2(z[11]);
        float p4 = EXP2(z[12]), p5 = EXP2(z[13]), p6 = EXP2(z[14]), p7 = EXP2(z[15]);
        ls += ((p0 + p1) + (p2 + p3)) + ((p4 + p5) + (p6 + p7));
        unsigned w0 = __builtin_amdgcn_perm(__float_as_uint(p1) + 0x8000u,
                                            __float_as_uint(p0) + 0x8000u, 0x07060302u);
        unsigned w1 = __builtin_amdgcn_perm(__float_as_uint(p3) + 0x8000u,
                                            __float_as_uint(p2) + 0x8000u, 0x07060302u);
        unsigned w2 = __builtin_amdgcn_perm(__float_as_uint(p5) + 0x8000u,
                                            __float_as_uint(p4) + 0x8000u, 0x07060302u);
        unsigned w3 = __builtin_amdgcn_perm(__float_as_uint(p7) + 0x8000u,
                                            __float_as_uint(p6) + 0x8000u, 0x07060302u);
        unsigned s0 = (unsigned)__shfl_xor((int)w0, 32);
        unsigned s1 = (unsigned)__shfl_xor((int)w1, 32);
        unsigned s2 = (unsigned)__shfl_xor((int)w2, 32);
        unsigned s3 = (unsigned)__shfl_xor((int)w3, 32);
        union { unsigned u[4]; bf16x8 v; } b1;
        b1.u[0] = hi ? s2 : w0;
        b1.u[1] = hi ? s3 : w1;
        b1.u[2] = hi ? w2 : s0;
        b1.u[3] = hi ? w3 : s1;
        bf16x8 vf0 = *(const bf16x8*)&KVt[cur][1][l31     ][((kh * 4 + 2 + hi) ^ (l31 & 7)) * 8];
        bf16x8 vf1 = *(const bf16x8*)&KVt[cur][1][32 + l31][((kh * 4 + 2 + hi) ^ (l31 & 7)) * 8];
        __builtin_amdgcn_s_setprio(1);
        o[0] = mfma32(vf0, b1.v, o[0]);
        o[1] = mfma32(vf1, b1.v, o[1]);
        __builtin_amdgcn_s_setprio(0);
      }
    }
    __syncthreads();   // next tile landed (vmcnt drain) + cur free for overwrite
  }

  // ---- epilogue: normalize own 32 q-rows, direct store ----
  const float lsum = ls + __shfl_xor(ls, 32);
  const float inv = 1.f / lsum;
  u16* Crow = CTX + (size_t)(b * SEQ + q0 + wave * 32 + l31) * DM + h * HD + hi * 4;
#pragma unroll
  for (int dh = 0; dh < 2; dh++)
#pragma unroll
    for (int g = 0; g < 4; g++) {
      union { u16 u[4]; uint2 w2; } tv;
#pragma unroll
      for (int r = 0; r < 4; r++)
        tv.u[r] = f2bf(o[dh][4 * g + r] * inv);
      *(uint2*)(Crow + dh * 32 + g * 8) = tv.w2;
    }
}

// ---------------- launch ----------------
extern "C" void kernel_launch(void* const* d_in, const int* in_sizes, int n_in,
                              void* d_out, int out_size, void* d_ws, size_t ws_size,
                              hipStream_t stream) {
  const float* x   = (const float*)d_in[0];
  const float* Wq  = (const float*)d_in[1];
  const float* bq  = (const float*)d_in[2];
  const float* Wkd = (const float*)d_in[3];
  const float* bkd = (const float*)d_in[4];
  const float* Wvd = (const float*)d_in[5];
  const float* bvd = (const float*)d_in[6];
  const float* Wku = (const float*)d_in[7];
  const float* bku = (const float*)d_in[8];
  const float* Wvu = (const float*)d_in[9];
  const float* bvu = (const float*)d_in[10];
  const float* Wo  = (const float*)d_in[11];
  const float* bo  = (const float*)d_in[12];
  float* out = (float*)d_out;

  float* bqkv = (float*)d_ws;
  u16* p = (u16*)((char*)d_ws + 1536 * sizeof(float));
  u16* xb    = p; p += (size_t)MTOT * DM;
  u16* WstkT = p; p += (size_t)NQKV * DM;           // WqT | WkdT | WvdT
  u16* WkuT  = p; p += (size_t)DM * LAT;
  u16* WvuT  = p; p += (size_t)DM * LAT;
  u16* WoT   = p; p += (size_t)DM * DM;
  u16* QKVb  = p; p += (size_t)MTOT * NQKV;         // Q(pre-scaled) | KL | VL
  u16* Kb    = p; p += (size_t)MTOT * DM;
  u16* VTb   = p; p += (size_t)MTOT * DM;
  u16* CXb   = p; p += (size_t)MTOT * DM;

  prep_k<<<4870, 256, 0, stream>>>(x, xb, Wq, Wkd, Wvd, Wku, Wvu, Wo,
                                   WstkT, WkuT, WvuT, WoT, bq, bkd, bvd, bqkv);

  // QKV projection: 24x32 = 768 blocks (3/CU)
  gemm_bt<128, 1, 0><<<dim3(NQKV / 64, MTOT / 128, 1), 256, 0, stream>>>(
      xb, xb, WstkT, WstkT, bqkv, bqkv, QKVb, QKVb, MTOT, NQKV, DM, DM, QSCALE, DM);
  // K-up (row layout) + V-up (transposed layout): 16x32x2 = 1024 blocks (4/CU)
  gemm_bt<128, 1, 1><<<dim3(DM / 64, MTOT / 128, 2), 256, 0, stream>>>(
      QKVb + 1024, QKVb + 1280, WkuT, WvuT, bku, bvu, Kb, VTb, MTOT, DM, LAT, NQKV, 1.f, 0);

  // 512 blocks x 256 threads: 16 q-blocks x 32 bh, XCD-remapped inside
  attn_fused<<<dim3(SEQ / 128, B_SZ * NH), 256, 0, stream>>>(QKVb, Kb, VTb, CXb);

  // output projection: 16x64 = 1024 blocks (4/CU)
  gemm_bt<64, 0, 0><<<dim3(DM / 64, MTOT / 64, 1), 256, 0, stream>>>(
      CXb, CXb, WoT, WoT, bo, bo, out, out, MTOT, DM, DM, DM, 1.f, 0);
}